// Round 7
// baseline (118.340 us; speedup 1.0000x reference)
//
#include <hip/hip_runtime.h>
#include <hip/hip_bf16.h>
#include <math.h>

#define XDIM 2048
#define OW   2033        // 2048 - 16 + 1
#define TR   32          // out rows per block tile
#define TC   256         // out cols per block tile
#define XW   272         // staged pair-words per image row (TC + 16)

typedef __bf16 bf16x8 __attribute__((ext_vector_type(8)));
typedef float  f32x16 __attribute__((ext_vector_type(16)));

union U128 { uint4 u; bf16x8 v; };

// 8-byte LDS access at 4-byte alignment -> compiler emits ds_read2_b32
struct __attribute__((packed, aligned(4))) W2 { unsigned int a, b; };

__device__ __forceinline__ unsigned short bfbits(float f) {
    return __builtin_bit_cast(unsigned short, __float2bfloat16(f));
}
// pair word: low16 = bf16(x^2) (plane p=0, weight w), high16 = bf16(x) (plane p=1, weight -2wk)
__device__ __forceinline__ unsigned int packx(float f) {
    return ((unsigned int)bfbits(f) << 16) | (unsigned int)bfbits(f * f);
}

__global__ __launch_bounds__(256) void psnr_mfma_kernel(
    const float* __restrict__ x,
    const float* __restrict__ kern,
    float* __restrict__ out)
{
    // X~ pairs for ONE channel (round-2 proven layout, word-granular)
    __shared__ __align__(16) unsigned int xt[47 * XW];            // 51.1 KB
    // W~ tables: 17 rows x 32-word stride, XOR-swizzled 16B groups:
    //   word j (=4q+e) of row i stored at i*32 + ((q ^ (i&7))<<2) + e
    // -> b128 reads stay aligned; lane banks spread (2-way max = free).
    __shared__ __align__(16) unsigned int wt[4][17 * 32];         // 8.7 KB
    __shared__ float skkArr[4];

    const int tid  = threadIdx.x;
    const int lane = tid & 63;
    const int wv   = tid >> 6;         // wave 0..3
    const int nn   = lane & 31;        // m for A-frags, n for B-frags
    const int hf   = lane >> 5;        // k-block half

    const int r0 = blockIdx.y * TR;
    const int c0 = blockIdx.x * TC;

    // ---------------- weight tables + Skk (once per block) ----------------
    {
        float k0 = kern[tid], k1 = kern[256 + tid], k2 = kern[512 + tid], k3 = kern[768 + tid];
        float a  = k3 * (1.0f / 255.0f);
        float om = 1.0f - a;
        float w  = om * om;
        int i = tid >> 4, j = tid & 15;          // row 0..15, word 0..15
        int q = j >> 2, e = j & 3;
        int addr = i * 32 + (((q ^ (i & 7)) << 2) + e);   // swizzled slot
        unsigned int wlo = (unsigned int)bfbits(w);
        wt[0][addr] = ((unsigned int)bfbits(-2.0f * w * k0) << 16) | wlo;
        wt[1][addr] = ((unsigned int)bfbits(-2.0f * w * k1) << 16) | wlo;
        wt[2][addr] = ((unsigned int)bfbits(-2.0f * w * k2) << 16) | wlo;
        wt[3][addr] = ((unsigned int)bfbits(-2.0f * w * k3) << 16) | wlo;
        if (tid < 128) {                         // zero row 16 (all 32 words)
            int c = tid >> 5, wd = tid & 31;
            wt[c][16 * 32 + wd] = 0u;
        }
        float4* red = reinterpret_cast<float4*>(&xt[0]);   // 4KB scratch before staging
        red[tid] = make_float4(w*k0*k0, w*k1*k1, w*k2*k2, w*k3*k3);
        __syncthreads();
        #pragma unroll
        for (int s = 128; s > 0; s >>= 1) {
            if (tid < s) {
                float4 o = red[tid + s], m = red[tid];
                m.x += o.x; m.y += o.y; m.z += o.z; m.w += o.w;
                red[tid] = m;
            }
            __syncthreads();
        }
        if (tid == 0) {
            float4 r0v = red[0];
            skkArr[0] = r0v.x; skkArr[1] = r0v.y; skkArr[2] = r0v.z; skkArr[3] = r0v.w;
        }
    }

    f32x16 psum0, psum1;
    #pragma unroll
    for (int q = 0; q < 16; ++q) { psum0[q] = 0.0f; psum1[q] = 0.0f; }

    const int xbase = nn + 4 * hf + (wv << 6);

    for (int ch = 0; ch < 4; ++ch) {
        __syncthreads();                 // previous users of xt done (covers wt/skk build)
        // ---------------- stage (x^2, x) bf16 pairs for this channel ----------------
        const float* __restrict__ xc = x + ((size_t)ch << 22);
        for (int idx = tid; idx < 47 * 68; idx += 256) {
            int row = idx / 68;
            int q4  = (idx - row * 68) * 4;          // pair col 0..268
            int gr  = r0 + row; if (gr > XDIM - 1) gr = XDIM - 1;
            int gc  = c0 + q4;
            const float* rp = xc + (size_t)gr * XDIM;
            float4 v;
            if (gc + 3 <= XDIM - 1) {
                v = *reinterpret_cast<const float4*>(rp + gc);
            } else {
                int e0 = gc     < XDIM ? gc     : XDIM - 1;
                int e1 = gc + 1 < XDIM ? gc + 1 : XDIM - 1;
                int e2 = gc + 2 < XDIM ? gc + 2 : XDIM - 1;
                int e3 = gc + 3 < XDIM ? gc + 3 : XDIM - 1;
                v = make_float4(rp[e0], rp[e1], rp[e2], rp[e3]);
            }
            *reinterpret_cast<uint4*>(&xt[row * XW + q4]) =
                make_uint4(packx(v.x), packx(v.y), packx(v.z), packx(v.w));
        }
        __syncthreads();

        // ---------------- MFMA i'-loop ----------------
        f32x16 acc0, acc1;
        #pragma unroll
        for (int q = 0; q < 16; ++q) { acc0[q] = 0.0f; acc1[q] = 0.0f; }

        const unsigned int* __restrict__ wch = &wt[ch][0];

        #pragma unroll 2
        for (int ip = 0; ip < 47; ++ip) {
            // A-frags: swizzled b128 reads; invalid rows -> broadcast zero row 16
            unsigned int d = (unsigned int)(ip - nn);
            unsigned int wrow = (d > 15u) ? 16u : d;
            unsigned int sw = wrow & 7u;
            const uint4* arow = reinterpret_cast<const uint4*>(wch + wrow * 32);
            U128 alo, ahi;
            alo.u = arow[hf ^ sw];
            ahi.u = arow[(2 + hf) ^ sw];

            // B-frags: Hankel windows as 8-byte align(4) loads -> ds_read2_b32
            int xb = ip * XW + xbase;
            const W2* bp = reinterpret_cast<const W2*>(&xt[xb]);
            U128 blo0, bhi0, blo1, bhi1;
            { W2 a0 = bp[0],  a1 = bp[1];  blo0.u = make_uint4(a0.a, a0.b, a1.a, a1.b); }
            { W2 a0 = bp[4],  a1 = bp[5];  bhi0.u = make_uint4(a0.a, a0.b, a1.a, a1.b); }
            { W2 a0 = bp[16], a1 = bp[17]; blo1.u = make_uint4(a0.a, a0.b, a1.a, a1.b); }
            { W2 a0 = bp[20], a1 = bp[21]; bhi1.u = make_uint4(a0.a, a0.b, a1.a, a1.b); }

            acc0 = __builtin_amdgcn_mfma_f32_32x32x16_bf16(alo.v, blo0.v, acc0, 0, 0, 0);
            acc0 = __builtin_amdgcn_mfma_f32_32x32x16_bf16(ahi.v, bhi0.v, acc0, 0, 0, 0);
            acc1 = __builtin_amdgcn_mfma_f32_32x32x16_bf16(alo.v, blo1.v, acc1, 0, 0, 0);
            acc1 = __builtin_amdgcn_mfma_f32_32x32x16_bf16(ahi.v, bhi1.v, acc1, 0, 0, 0);
        }

        // ---------------- per-channel epilogue: mse -> log2 accumulate ----------------
        float sk = skkArr[ch];
        #pragma unroll
        for (int q = 0; q < 16; ++q) {
            float m0 = (acc0[q] + sk) * (1.0f / 256.0f);
            float m1 = (acc1[q] + sk) * (1.0f / 256.0f);
            psum0[q] += __log2f(m0);
            psum1[q] += __log2f(m1);
        }
    }

    // psnr = 20log10(255) - 2.5 * sum_c log10(mse_c);  log10 = log2 * 0.30103
    const float BASE = 48.130803608679344f;
    const float SC   = 2.5f * 0.3010299956639812f;
    const int col0 = c0 + (wv << 6) + nn;
    const int col1 = col0 + 32;
    #pragma unroll
    for (int q = 0; q < 16; ++q) {
        int row = r0 + (q & 3) + ((q >> 2) << 3) + (hf << 2);
        if (row < OW) {
            float* orow = out + (size_t)row * OW;
            if (col0 < OW) orow[col0] = BASE - SC * psum0[q];
            if (col1 < OW) orow[col1] = BASE - SC * psum1[q];
        }
    }
}

extern "C" void kernel_launch(void* const* d_in, const int* in_sizes, int n_in,
                              void* d_out, int out_size, void* d_ws, size_t ws_size,
                              hipStream_t stream) {
    (void)in_sizes; (void)n_in; (void)d_ws; (void)ws_size; (void)out_size;
    const float* x    = (const float*)d_in[0];
    const float* kern = (const float*)d_in[1];
    float* out        = (float*)d_out;

    dim3 grid(XDIM / TC, (OW + TR - 1) / TR);   // 8 x 64 = 512 blocks
    psnr_mfma_kernel<<<grid, 256, 0, stream>>>(x, kern, out);
}

// Round 8
// 105.140 us; speedup vs baseline: 1.1255x; 1.1255x over previous
//
#include <hip/hip_runtime.h>
#include <hip/hip_bf16.h>
#include <math.h>

#define XDIM 2048
#define OW   2033        // 2048 - 16 + 1
#define TR   32          // out rows per block tile
#define TC   256         // out cols per block tile
#define XWP  272         // staged pair-cols per image row (TC + 16)
#define NIT  13          // ceil(47*68 / 256) staging items per thread
#define NITEMS (47*68)   // 3196 items per channel tile (item = 4 pair-cols)

typedef __bf16 bf16x8 __attribute__((ext_vector_type(8)));
typedef float  f32x16 __attribute__((ext_vector_type(16)));

union U128 { uint4 u; bf16x8 v; };

__device__ __forceinline__ unsigned short bfbits(float f) {
    return __builtin_bit_cast(unsigned short, __float2bfloat16(f));
}
// pair word: low16 = bf16(x^2) (plane p=0, weight w), high16 = bf16(x) (plane p=1, weight -2wk)
__device__ __forceinline__ unsigned int packx(float f) {
    return ((unsigned int)bfbits(f) << 16) | (unsigned int)bfbits(f * f);
}
// XOR bank swizzle on PAIR index: touches bits 1..3 only -> pair adjacency
// (bit0) preserved, 16B write alignment preserved, bijective within 16-slot
// groups. Spreads staging-write start banks over 8 groups (was 8-way conflict)
// and keeps Hankel b64 reads uniform across banks.
__device__ __forceinline__ int slz(int c) {
    return c ^ (((c >> 2) & 7) << 1);
}

__global__ __launch_bounds__(256) void psnr_mfma_kernel(
    const float* __restrict__ x,
    const float* __restrict__ kern,
    float* __restrict__ out)
{
    // Overlapped pairs, swizzled slots: row ip, pair-slot slz(c) = (P[c],P[c+1]).
    // Any 4-word Hankel window [c..c+3] = two ds_read_b64 at slz(c), slz(c+2).
    __shared__ __align__(16) uint2 xtp[47][XWP];                  // 102.3 KB -> 1 block/CU
    __shared__ __align__(16) unsigned int wt[4][17 * 20];         // 5.44 KB (r2 layout)
    __shared__ float skkArr[4];

    const int tid  = threadIdx.x;
    const int lane = tid & 63;
    const int wv   = tid >> 6;         // wave 0..3
    const int nn   = lane & 31;        // m for A-frags, n for B-frags
    const int hf   = lane >> 5;        // k-block half

    const int r0 = blockIdx.y * TR;
    const int c0 = blockIdx.x * TC;

    // ---- prefetch registers (static indexing; at 1 wave/SIMD VGPRs are free) ----
    float4 pf[NIT];
    float  pe[NIT];

    auto issue = [&](int ch) {
        const float* __restrict__ xc = x + ((size_t)ch << 22);
        #pragma unroll
        for (int t = 0; t < NIT; ++t) {
            int idx = tid + 256 * t;
            if (idx < NITEMS) {
                int row = idx / 68;
                int it  = idx - row * 68;
                int gr  = r0 + row; if (gr > XDIM - 1) gr = XDIM - 1;
                int gc  = c0 + it * 4;
                const float* rp = xc + (size_t)gr * XDIM;
                if (gc + 3 <= XDIM - 1) {
                    pf[t] = *reinterpret_cast<const float4*>(rp + gc);
                } else {
                    int e0 = gc     < XDIM ? gc     : XDIM - 1;
                    int e1 = gc + 1 < XDIM ? gc + 1 : XDIM - 1;
                    int e2 = gc + 2 < XDIM ? gc + 2 : XDIM - 1;
                    int e3 = gc + 3 < XDIM ? gc + 3 : XDIM - 1;
                    pf[t] = make_float4(rp[e0], rp[e1], rp[e2], rp[e3]);
                }
                int e4 = gc + 4 < XDIM ? gc + 4 : XDIM - 1;
                pe[t] = rp[e4];
            }
        }
    };

    auto wrt = [&]() {
        #pragma unroll
        for (int t = 0; t < NIT; ++t) {
            int idx = tid + 256 * t;
            if (idx < NITEMS) {
                int row = idx / 68;
                int it  = idx - row * 68;
                float4 v = pf[t];
                unsigned int P0 = packx(v.x), P1 = packx(v.y), P2 = packx(v.z),
                             P3 = packx(v.w), P4 = packx(pe[t]);
                int s   = (it & 7) << 1;
                int sl0 = (4 * it)     ^ s;      // slots for pairs p, p+1
                int sl2 = (4 * it + 2) ^ s;      // slots for pairs p+2, p+3
                uint2* base = &xtp[row][0];
                *reinterpret_cast<uint4*>(base + sl0) = make_uint4(P0, P1, P1, P2);
                *reinterpret_cast<uint4*>(base + sl2) = make_uint4(P2, P3, P3, P4);
            }
        }
    };

    // ---- channel 0 loads in flight under the weight-table build ----
    issue(0);

    // ---------------- weight tables + Skk (once per block, r2-proven) ----------------
    {
        float k0 = kern[tid], k1 = kern[256 + tid], k2 = kern[512 + tid], k3 = kern[768 + tid];
        float a  = k3 * (1.0f / 255.0f);
        float om = 1.0f - a;
        float w  = om * om;
        int i = tid >> 4, j = tid & 15;
        unsigned int wlo = (unsigned int)bfbits(w);
        wt[0][i * 20 + j] = ((unsigned int)bfbits(-2.0f * w * k0) << 16) | wlo;
        wt[1][i * 20 + j] = ((unsigned int)bfbits(-2.0f * w * k1) << 16) | wlo;
        wt[2][i * 20 + j] = ((unsigned int)bfbits(-2.0f * w * k2) << 16) | wlo;
        wt[3][i * 20 + j] = ((unsigned int)bfbits(-2.0f * w * k3) << 16) | wlo;
        if (tid < 80) {                       // zero row 16 of each channel table
            int c = tid / 20, wd = tid % 20;
            wt[c][16 * 20 + wd] = 0u;
        }
        float4* red = reinterpret_cast<float4*>(&xtp[0][0]);   // 4KB scratch pre-staging
        red[tid] = make_float4(w*k0*k0, w*k1*k1, w*k2*k2, w*k3*k3);
        __syncthreads();
        #pragma unroll
        for (int s = 128; s > 0; s >>= 1) {
            if (tid < s) {
                float4 o = red[tid + s], m = red[tid];
                m.x += o.x; m.y += o.y; m.z += o.z; m.w += o.w;
                red[tid] = m;
            }
            __syncthreads();
        }
        if (tid == 0) {
            float4 r0v = red[0];
            skkArr[0] = r0v.x; skkArr[1] = r0v.y; skkArr[2] = r0v.z; skkArr[3] = r0v.w;
        }
        __syncthreads();   // wt/skk visible; xtp scratch done
    }

    f32x16 psum0, psum1;
    #pragma unroll
    for (int q = 0; q < 16; ++q) { psum0[q] = 0.0f; psum1[q] = 0.0f; }

    // B-read pair offsets are ip-invariant: swizzle them ONCE.
    const int xbase = nn + 4 * hf;
    const int o0 = slz(xbase),      o1 = slz(xbase + 2);    // lo frag, col-group 0
    const int o2 = slz(xbase + 8),  o3 = slz(xbase + 10);   // hi frag, col-group 0
    const int o4 = slz(xbase + 32), o5 = slz(xbase + 34);   // lo frag, col-group 1
    const int o6 = slz(xbase + 40), o7 = slz(xbase + 42);   // hi frag, col-group 1
    const int wvoff = (wv << 6);    // wave's col offset applied via swizzle-safe base?
    // NOTE: wave offset is 64 = multiple of 16, and slz only mixes bits 1..3,
    // so slz(c + 64) == slz(c) + 64: fold it into the offsets.
    const int p0 = o0 + wvoff, p1 = o1 + wvoff, p2 = o2 + wvoff, p3 = o3 + wvoff;
    const int p4 = o4 + wvoff, p5 = o5 + wvoff, p6 = o6 + wvoff, p7 = o7 + wvoff;

    for (int ch = 0; ch < 4; ++ch) {
        __syncthreads();                 // previous users of xtp done
        wrt();                           // pack prefetched channel into LDS
        __syncthreads();
        if (ch < 3) issue(ch + 1);       // next channel's loads fly under compute

        f32x16 acc0, acc1;
        #pragma unroll
        for (int q = 0; q < 16; ++q) { acc0[q] = 0.0f; acc1[q] = 0.0f; }

        const unsigned int* __restrict__ wch = &wt[ch][0];

        for (int ip = 0; ip < 47; ++ip) {
            // A-frags: r2-proven b128 reads; invalid rows -> zero row 16
            unsigned int d = (unsigned int)(ip - nn);
            unsigned int wrow = (d > 15u) ? 16u : d;
            U128 alo, ahi;
            alo.u = *reinterpret_cast<const uint4*>(wch + wrow * 20 + hf * 4);
            ahi.u = *reinterpret_cast<const uint4*>(wch + wrow * 20 + 8 + hf * 4);

            // B-frags: 8 aligned ds_read_b64 from swizzled pair slots
            const uint2* __restrict__ bp = &xtp[ip][0];
            U128 blo0, bhi0, blo1, bhi1;
            { uint2 a0 = bp[p0], a1 = bp[p1]; blo0.u = make_uint4(a0.x, a0.y, a1.x, a1.y); }
            { uint2 a0 = bp[p2], a1 = bp[p3]; bhi0.u = make_uint4(a0.x, a0.y, a1.x, a1.y); }
            { uint2 a0 = bp[p4], a1 = bp[p5]; blo1.u = make_uint4(a0.x, a0.y, a1.x, a1.y); }
            { uint2 a0 = bp[p6], a1 = bp[p7]; bhi1.u = make_uint4(a0.x, a0.y, a1.x, a1.y); }

            acc0 = __builtin_amdgcn_mfma_f32_32x32x16_bf16(alo.v, blo0.v, acc0, 0, 0, 0);
            acc0 = __builtin_amdgcn_mfma_f32_32x32x16_bf16(ahi.v, bhi0.v, acc0, 0, 0, 0);
            acc1 = __builtin_amdgcn_mfma_f32_32x32x16_bf16(alo.v, blo1.v, acc1, 0, 0, 0);
            acc1 = __builtin_amdgcn_mfma_f32_32x32x16_bf16(ahi.v, bhi1.v, acc1, 0, 0, 0);
        }

        // per-channel epilogue: mse -> fast log2 accumulate
        float sk = skkArr[ch];
        #pragma unroll
        for (int q = 0; q < 16; ++q) {
            float m0 = (acc0[q] + sk) * (1.0f / 256.0f);
            float m1 = (acc1[q] + sk) * (1.0f / 256.0f);
            psum0[q] += __log2f(m0);
            psum1[q] += __log2f(m1);
        }
    }

    // psnr = 20log10(255) - 2.5 * sum_c log10(mse_c);  log10 = log2 * 0.30103
    const float BASE = 48.130803608679344f;
    const float SC   = 2.5f * 0.3010299956639812f;
    const int col0 = c0 + (wv << 6) + nn;
    const int col1 = col0 + 32;
    #pragma unroll
    for (int q = 0; q < 16; ++q) {
        int row = r0 + (q & 3) + ((q >> 2) << 3) + (hf << 2);
        if (row < OW) {
            float* orow = out + (size_t)row * OW;
            if (col0 < OW) orow[col0] = BASE - SC * psum0[q];
            if (col1 < OW) orow[col1] = BASE - SC * psum1[q];
        }
    }
}

extern "C" void kernel_launch(void* const* d_in, const int* in_sizes, int n_in,
                              void* d_out, int out_size, void* d_ws, size_t ws_size,
                              hipStream_t stream) {
    (void)in_sizes; (void)n_in; (void)d_ws; (void)ws_size; (void)out_size;
    const float* x    = (const float*)d_in[0];
    const float* kern = (const float*)d_in[1];
    float* out        = (float*)d_out;

    dim3 grid(XDIM / TC, (OW + TR - 1) / TR);   // 8 x 64 = 512 blocks
    psnr_mfma_kernel<<<grid, 256, 0, stream>>>(x, kern, out);
}

// Round 9
// 66.092 us; speedup vs baseline: 1.7905x; 1.5908x over previous
//
#include <hip/hip_runtime.h>
#include <hip/hip_bf16.h>
#include <math.h>

#define XDIM 2048
#define OW   2033        // 2048 - 16 + 1
#define TR   32          // out rows per block tile
#define TC   256         // out cols per block tile
#define XWP  272         // staged pair-cols per image row (TC + 16)
#define PH   16          // rows per staging phase (3 phases: 16,16,15)

typedef __bf16 bf16x8 __attribute__((ext_vector_type(8)));
typedef float  f32x16 __attribute__((ext_vector_type(16)));

union U128 { uint4 u; bf16x8 v; };

__device__ __forceinline__ unsigned short bfbits(float f) {
    return __builtin_bit_cast(unsigned short, __float2bfloat16(f));
}
// pair word: low16 = bf16(x^2) (plane p=0, weight w), high16 = bf16(x) (plane p=1, weight -2wk)
__device__ __forceinline__ unsigned int packx(float f) {
    return ((unsigned int)bfbits(f) << 16) | (unsigned int)bfbits(f * f);
}
// XOR bank swizzle on PAIR index (bits 1..3 only): pair adjacency and 16B
// write alignment preserved; bijective within 16-slot groups. Proven r8:
// staging-write conflicts stay at baseline (1.16e6).
__device__ __forceinline__ int slz(int c) {
    return c ^ (((c >> 2) & 7) << 1);
}

__global__ __launch_bounds__(256) void psnr_mfma_kernel(
    const float* __restrict__ x,
    const float* __restrict__ kern,
    float* __restrict__ out)
{
    // 16-row pair buffer, re-staged 3x per channel. Overlapped pairs
    // T[slz(c)] = (P[c], P[c+1]): any 4-word Hankel window = 2x ds_read_b64.
    // 34.8KB + 5.4KB -> 4 blocks/CU resident (the round-8 fix).
    __shared__ __align__(16) uint2 xtp[PH][XWP];                  // 34.8 KB
    __shared__ __align__(16) unsigned int wt[4][17 * 20];         // 5.44 KB
    __shared__ float skkArr[4];

    const int tid  = threadIdx.x;
    const int lane = tid & 63;
    const int wv   = tid >> 6;         // wave 0..3
    const int nn   = lane & 31;        // m for A-frags, n for B-frags
    const int hf   = lane >> 5;        // k-block half

    const int r0 = blockIdx.y * TR;
    const int c0 = blockIdx.x * TC;

    // ---------------- weight tables + Skk (once per block, r2-proven) ----------------
    {
        float k0 = kern[tid], k1 = kern[256 + tid], k2 = kern[512 + tid], k3 = kern[768 + tid];
        float a  = k3 * (1.0f / 255.0f);
        float om = 1.0f - a;
        float w  = om * om;
        int i = tid >> 4, j = tid & 15;
        unsigned int wlo = (unsigned int)bfbits(w);
        wt[0][i * 20 + j] = ((unsigned int)bfbits(-2.0f * w * k0) << 16) | wlo;
        wt[1][i * 20 + j] = ((unsigned int)bfbits(-2.0f * w * k1) << 16) | wlo;
        wt[2][i * 20 + j] = ((unsigned int)bfbits(-2.0f * w * k2) << 16) | wlo;
        wt[3][i * 20 + j] = ((unsigned int)bfbits(-2.0f * w * k3) << 16) | wlo;
        if (tid < 80) {                       // zero row 16 of each channel table
            int c = tid / 20, wd = tid % 20;
            wt[c][16 * 20 + wd] = 0u;
        }
        float4* red = reinterpret_cast<float4*>(&xtp[0][0]);   // 4KB scratch pre-staging
        red[tid] = make_float4(w*k0*k0, w*k1*k1, w*k2*k2, w*k3*k3);
        __syncthreads();
        #pragma unroll
        for (int s = 128; s > 0; s >>= 1) {
            if (tid < s) {
                float4 o = red[tid + s], m = red[tid];
                m.x += o.x; m.y += o.y; m.z += o.z; m.w += o.w;
                red[tid] = m;
            }
            __syncthreads();
        }
        if (tid == 0) {
            float4 r0v = red[0];
            skkArr[0] = r0v.x; skkArr[1] = r0v.y; skkArr[2] = r0v.z; skkArr[3] = r0v.w;
        }
    }

    f32x16 psum0, psum1;
    #pragma unroll
    for (int q = 0; q < 16; ++q) { psum0[q] = 0.0f; psum1[q] = 0.0f; }

    // B-read pair slots are ip-invariant: swizzle once. slz(c+64)=slz(c)+64,
    // so the wave's 64-pair col offset folds in linearly.
    const int xbase = nn + 4 * hf;
    const int wvoff = (wv << 6);
    const int p0 = slz(xbase)      + wvoff, p1 = slz(xbase + 2)  + wvoff;
    const int p2 = slz(xbase + 8)  + wvoff, p3 = slz(xbase + 10) + wvoff;
    const int p4 = slz(xbase + 32) + wvoff, p5 = slz(xbase + 34) + wvoff;
    const int p6 = slz(xbase + 40) + wvoff, p7 = slz(xbase + 42) + wvoff;

    for (int ch = 0; ch < 4; ++ch) {
        const float* __restrict__ xc = x + ((size_t)ch << 22);

        f32x16 acc0, acc1;
        #pragma unroll
        for (int q = 0; q < 16; ++q) { acc0[q] = 0.0f; acc1[q] = 0.0f; }

        #pragma unroll
        for (int ph = 0; ph < 3; ++ph) {
            const int base = ph * PH;
            const int nr   = (ph == 2) ? 15 : 16;

            __syncthreads();               // previous phase's readers done
            // ---- stage nr rows of (x^2, x) pairs, swizzled slots ----
            for (int idx = tid; idx < nr * 68; idx += 256) {
                int row = idx / 68;
                int it  = idx - row * 68;
                int gr  = r0 + base + row; if (gr > XDIM - 1) gr = XDIM - 1;
                int gc  = c0 + it * 4;
                const float* rp = xc + (size_t)gr * XDIM;
                float4 v;
                if (gc + 3 <= XDIM - 1) {
                    v = *reinterpret_cast<const float4*>(rp + gc);
                } else {
                    int e0 = gc     < XDIM ? gc     : XDIM - 1;
                    int e1 = gc + 1 < XDIM ? gc + 1 : XDIM - 1;
                    int e2 = gc + 2 < XDIM ? gc + 2 : XDIM - 1;
                    int e3 = gc + 3 < XDIM ? gc + 3 : XDIM - 1;
                    v = make_float4(rp[e0], rp[e1], rp[e2], rp[e3]);
                }
                int e4 = gc + 4 < XDIM ? gc + 4 : XDIM - 1;
                float x4 = rp[e4];

                unsigned int P0 = packx(v.x), P1 = packx(v.y), P2 = packx(v.z),
                             P3 = packx(v.w), P4 = packx(x4);
                int s   = (it & 7) << 1;
                int sl0 = (4 * it)     ^ s;
                int sl2 = (4 * it + 2) ^ s;
                uint2* bb = &xtp[row][0];
                *reinterpret_cast<uint4*>(bb + sl0) = make_uint4(P0, P1, P1, P2);
                *reinterpret_cast<uint4*>(bb + sl2) = make_uint4(P2, P3, P3, P4);
            }
            __syncthreads();

            // ---- MFMA over this phase's ips ----
            const unsigned int* __restrict__ wch = &wt[ch][0];
            for (int r = 0; r < nr; ++r) {
                int ip = base + r;
                // A-frags: b128 from weight table; invalid rows -> zero row 16
                unsigned int d = (unsigned int)(ip - nn);
                unsigned int wrow = (d > 15u) ? 16u : d;
                U128 alo, ahi;
                alo.u = *reinterpret_cast<const uint4*>(wch + wrow * 20 + hf * 4);
                ahi.u = *reinterpret_cast<const uint4*>(wch + wrow * 20 + 8 + hf * 4);

                // B-frags: 8 aligned ds_read_b64 from swizzled pair slots
                const uint2* __restrict__ bp = &xtp[r][0];
                U128 blo0, bhi0, blo1, bhi1;
                { uint2 a0 = bp[p0], a1 = bp[p1]; blo0.u = make_uint4(a0.x, a0.y, a1.x, a1.y); }
                { uint2 a0 = bp[p2], a1 = bp[p3]; bhi0.u = make_uint4(a0.x, a0.y, a1.x, a1.y); }
                { uint2 a0 = bp[p4], a1 = bp[p5]; blo1.u = make_uint4(a0.x, a0.y, a1.x, a1.y); }
                { uint2 a0 = bp[p6], a1 = bp[p7]; bhi1.u = make_uint4(a0.x, a0.y, a1.x, a1.y); }

                acc0 = __builtin_amdgcn_mfma_f32_32x32x16_bf16(alo.v, blo0.v, acc0, 0, 0, 0);
                acc0 = __builtin_amdgcn_mfma_f32_32x32x16_bf16(ahi.v, bhi0.v, acc0, 0, 0, 0);
                acc1 = __builtin_amdgcn_mfma_f32_32x32x16_bf16(alo.v, blo1.v, acc1, 0, 0, 0);
                acc1 = __builtin_amdgcn_mfma_f32_32x32x16_bf16(ahi.v, bhi1.v, acc1, 0, 0, 0);
            }
        }

        // per-channel epilogue: mse -> fast log2 accumulate
        float sk = skkArr[ch];
        #pragma unroll
        for (int q = 0; q < 16; ++q) {
            float m0 = (acc0[q] + sk) * (1.0f / 256.0f);
            float m1 = (acc1[q] + sk) * (1.0f / 256.0f);
            psum0[q] += __log2f(m0);
            psum1[q] += __log2f(m1);
        }
    }

    // psnr = 20log10(255) - 2.5 * sum_c log10(mse_c);  log10 = log2 * 0.30103
    const float BASE = 48.130803608679344f;
    const float SC   = 2.5f * 0.3010299956639812f;
    const int col0 = c0 + (wv << 6) + nn;
    const int col1 = col0 + 32;
    #pragma unroll
    for (int q = 0; q < 16; ++q) {
        int row = r0 + (q & 3) + ((q >> 2) << 3) + (hf << 2);
        if (row < OW) {
            float* orow = out + (size_t)row * OW;
            if (col0 < OW) orow[col0] = BASE - SC * psum0[q];
            if (col1 < OW) orow[col1] = BASE - SC * psum1[q];
        }
    }
}

extern "C" void kernel_launch(void* const* d_in, const int* in_sizes, int n_in,
                              void* d_out, int out_size, void* d_ws, size_t ws_size,
                              hipStream_t stream) {
    (void)in_sizes; (void)n_in; (void)d_ws; (void)ws_size; (void)out_size;
    const float* x    = (const float*)d_in[0];
    const float* kern = (const float*)d_in[1];
    float* out        = (float*)d_out;

    dim3 grid(XDIM / TC, (OW + TR - 1) / TR);   // 8 x 64 = 512 blocks
    psnr_mfma_kernel<<<grid, 256, 0, stream>>>(x, kern, out);
}